// Round 1
// baseline (275.052 us; speedup 1.0000x reference)
//
#include <hip/hip_runtime.h>
#include <math.h>

#define NNODE 100000
#define NREL 2000
#define NEDGE 600000
#define DIM 128
#define NDEPTH 2
#define OUTC 384   // DIM*(NDEPTH+1)

__device__ __forceinline__ float wave_sum(float v) {
#pragma unroll
    for (int off = 32; off > 0; off >>= 1)
        v += __shfl_xor(v, off, 64);
    return v;
}

// relu(features) -> d_out columns [0,128)
__global__ void k_relu_in(const float* __restrict__ f, float* __restrict__ out) {
    int idx = blockIdx.x * blockDim.x + threadIdx.x;
    if (idx >= NNODE * (DIM / 4)) return;
    int n = idx >> 5;   // 32 float4 per row
    int q = idx & 31;
    float4 v = reinterpret_cast<const float4*>(f + (size_t)n * DIM)[q];
    v.x = fmaxf(v.x, 0.f); v.y = fmaxf(v.y, 0.f);
    v.z = fmaxf(v.z, 0.f); v.w = fmaxf(v.w, 0.f);
    reinterpret_cast<float4*>(out + (size_t)n * OUTC)[q] = v;
}

// ||rel_emb[r]||^2, one wave per relation
__global__ void k_rel_norm(const float* __restrict__ rel, float* __restrict__ relnorm2) {
    int wid = (blockIdx.x * blockDim.x + threadIdx.x) >> 6;
    int lane = threadIdx.x & 63;
    if (wid >= NREL) return;
    float2 v = reinterpret_cast<const float2*>(rel + (size_t)wid * DIM)[lane];
    float p = wave_sum(v.x * v.x + v.y * v.y);
    if (lane == 0) relnorm2[wid] = p;
}

// per-relation dots with attn kernel parts B and C (layer-dependent)
__global__ void k_rel_dots(const float* __restrict__ rel, const float* __restrict__ ak,
                           float* __restrict__ rdB, float* __restrict__ rdC) {
    int wid = (blockIdx.x * blockDim.x + threadIdx.x) >> 6;
    int lane = threadIdx.x & 63;
    if (wid >= NREL) return;
    float2 v = reinterpret_cast<const float2*>(rel + (size_t)wid * DIM)[lane];
    float2 b = reinterpret_cast<const float2*>(ak + DIM)[lane];
    float2 c = reinterpret_cast<const float2*>(ak + 2 * DIM)[lane];
    float pb = wave_sum(v.x * b.x + v.y * b.y);
    float pc = wave_sum(v.x * c.x + v.y * c.y);
    if (lane == 0) { rdB[wid] = pb; rdC[wid] = pc; }
}

// per-edge normalization scalar: sp_val * rsqrt(max(sp_val^2*||rel||^2, 1e-12))
__global__ void k_scale(const float* __restrict__ sp_val, const int* __restrict__ sp_rel,
                        const float* __restrict__ relnorm2, float* __restrict__ scale) {
    int e = blockIdx.x * blockDim.x + threadIdx.x;
    if (e >= NEDGE) return;
    float v = sp_val[e];
    float n2 = v * v * relnorm2[sp_rel[e]];
    scale[e] = v * rsqrtf(fmaxf(n2, 1e-12f));
}

// CSR row_ptr by binary search over sorted adj_src
__global__ void k_rowptr(const int* __restrict__ adj_src, int* __restrict__ row_ptr) {
    int n = blockIdx.x * blockDim.x + threadIdx.x;
    if (n > NNODE) return;
    int lo = 0, hi = NEDGE;
    while (lo < hi) {
        int mid = (lo + hi) >> 1;
        if (adj_src[mid] < n) lo = mid + 1; else hi = mid;
    }
    row_ptr[n] = lo;
}

// per-node dots with attn kernel parts A (self) and B (neigh)
__global__ void k_node_dots(const float* __restrict__ feats, const float* __restrict__ ak,
                            float* __restrict__ selfdot, float* __restrict__ neighdot) {
    int wid = (blockIdx.x * blockDim.x + threadIdx.x) >> 6;
    int lane = threadIdx.x & 63;
    if (wid >= NNODE) return;
    float2 f = reinterpret_cast<const float2*>(feats + (size_t)wid * OUTC)[lane];
    float2 a = reinterpret_cast<const float2*>(ak)[lane];
    float2 b = reinterpret_cast<const float2*>(ak + DIM)[lane];
    float pa = wave_sum(f.x * a.x + f.y * a.y);
    float pb = wave_sum(f.x * b.x + f.y * b.y);
    if (lane == 0) { selfdot[wid] = pa; neighdot[wid] = pb; }
}

// one wave per node: flash-style online softmax + Householder-reflected aggregation
__global__ void k_gat(const float* __restrict__ feats_in, float* __restrict__ feats_out,
                      const float* __restrict__ rel_emb,
                      const int* __restrict__ adj_dst, const int* __restrict__ sp_rel,
                      const float* __restrict__ scale,
                      const float* __restrict__ selfdot, const float* __restrict__ neighdot,
                      const float* __restrict__ rdB, const float* __restrict__ rdC,
                      const int* __restrict__ row_ptr) {
    int wid = (blockIdx.x * blockDim.x + threadIdx.x) >> 6;
    int lane = threadIdx.x & 63;
    if (wid >= NNODE) return;
    int e0 = row_ptr[wid], e1 = row_ptr[wid + 1];
    float2 acc = make_float2(0.f, 0.f);
    float m = -INFINITY, s = 0.f;
    float sd = selfdot[wid];
    for (int e = e0; e < e1; ++e) {
        int dst = adj_dst[e];
        int r   = sp_rel[e];
        float sc = scale[e];
        float2 f  = reinterpret_cast<const float2*>(feats_in + (size_t)dst * OUTC)[lane];
        float2 rv = reinterpret_cast<const float2*>(rel_emb + (size_t)r * DIM)[lane];
        float c = sc * wave_sum(f.x * rv.x + f.y * rv.y);
        float att = sd + neighdot[dst] + sc * (rdC[r] - 2.f * c * rdB[r]);
        float nm = fmaxf(m, att);
        float corr = __expf(m - nm);     // m = -inf on first iter -> 0
        float w = __expf(att - nm);
        s = s * corr + w;
        float k2 = 2.f * c * sc;
        acc.x = acc.x * corr + w * (f.x - k2 * rv.x);
        acc.y = acc.y * corr + w * (f.y - k2 * rv.y);
        m = nm;
    }
    float2 o = make_float2(0.f, 0.f);
    if (e1 > e0) {
        float inv = 1.f / s;
        o.x = fmaxf(acc.x * inv, 0.f);
        o.y = fmaxf(acc.y * inv, 0.f);
    }
    reinterpret_cast<float2*>(feats_out + (size_t)wid * OUTC)[lane] = o;
}

extern "C" void kernel_launch(void* const* d_in, const int* in_sizes, int n_in,
                              void* d_out, int out_size, void* d_ws, size_t ws_size,
                              hipStream_t stream) {
    const float* features = (const float*)d_in[0];
    const float* rel_emb  = (const float*)d_in[1];
    const float* sp_val   = (const float*)d_in[2];
    const float* attn     = (const float*)d_in[3];
    const int*   adj_src  = (const int*)d_in[4];
    const int*   adj_dst  = (const int*)d_in[5];
    const int*   sp_rel   = (const int*)d_in[6];
    // d_in[7] = sp_row = arange(E) -> identity segment_sum, unused
    float* out = (float*)d_out;

    char* ws = (char*)d_ws;
    float* scale    = (float*)ws; ws += (size_t)NEDGE * sizeof(float);
    float* selfdot  = (float*)ws; ws += (size_t)NNODE * sizeof(float);
    float* neighdot = (float*)ws; ws += (size_t)NNODE * sizeof(float);
    float* relnorm2 = (float*)ws; ws += (size_t)NREL * sizeof(float);
    float* rdB      = (float*)ws; ws += (size_t)NREL * sizeof(float);
    float* rdC      = (float*)ws; ws += (size_t)NREL * sizeof(float);
    int*   row_ptr  = (int*)ws;   ws += (size_t)(NNODE + 1) * sizeof(int);

    k_relu_in<<<(NNODE * 32 + 255) / 256, 256, 0, stream>>>(features, out);
    k_rel_norm<<<(NREL * 64 + 255) / 256, 256, 0, stream>>>(rel_emb, relnorm2);
    k_scale<<<(NEDGE + 255) / 256, 256, 0, stream>>>(sp_val, sp_rel, relnorm2, scale);
    k_rowptr<<<(NNODE + 1 + 255) / 256, 256, 0, stream>>>(adj_src, row_ptr);

    for (int l = 0; l < NDEPTH; ++l) {
        const float* ak  = attn + (size_t)l * 3 * DIM;
        const float* fin = out + (size_t)l * DIM;
        float*       fout = out + (size_t)(l + 1) * DIM;
        k_rel_dots<<<(NREL * 64 + 255) / 256, 256, 0, stream>>>(rel_emb, ak, rdB, rdC);
        k_node_dots<<<(NNODE * 64 + 255) / 256, 256, 0, stream>>>(fin, ak, selfdot, neighdot);
        k_gat<<<(NNODE * 64 + 255) / 256, 256, 0, stream>>>(fin, fout, rel_emb, adj_dst, sp_rel,
                                                            scale, selfdot, neighdot, rdB, rdC, row_ptr);
    }
}

// Round 2
// 226.565 us; speedup vs baseline: 1.2140x; 1.2140x over previous
//
#include <hip/hip_runtime.h>
#include <math.h>

#define NNODE 100000
#define NREL 2000
#define NEDGE 600000
#define DIM 128
#define NDEPTH 2
#define OUTC 384   // DIM*(DEPTH+1)

__device__ __forceinline__ float wave_sum(float v) {
#pragma unroll
    for (int off = 32; off > 0; off >>= 1)
        v += __shfl_xor(v, off, 64);
    return v;
}

// relu(features) -> d_out columns [0,128)
__global__ void k_relu_in(const float* __restrict__ f, float* __restrict__ out) {
    int idx = blockIdx.x * blockDim.x + threadIdx.x;
    if (idx >= NNODE * (DIM / 4)) return;
    int n = idx >> 5;   // 32 float4 per row
    int q = idx & 31;
    float4 v = reinterpret_cast<const float4*>(f + (size_t)n * DIM)[q];
    v.x = fmaxf(v.x, 0.f); v.y = fmaxf(v.y, 0.f);
    v.z = fmaxf(v.z, 0.f); v.w = fmaxf(v.w, 0.f);
    reinterpret_cast<float4*>(out + (size_t)n * OUTC)[q] = v;
}

// ||rel_emb[r]||^2, one wave per relation
__global__ void k_rel_norm(const float* __restrict__ rel, float* __restrict__ relnorm2) {
    int wid = (blockIdx.x * blockDim.x + threadIdx.x) >> 6;
    int lane = threadIdx.x & 63;
    if (wid >= NREL) return;
    float2 v = reinterpret_cast<const float2*>(rel + (size_t)wid * DIM)[lane];
    float p = wave_sum(v.x * v.x + v.y * v.y);
    if (lane == 0) relnorm2[wid] = p;
}

// per-relation dots with attn kernel parts B and C (layer-dependent)
__global__ void k_rel_dots(const float* __restrict__ rel, const float* __restrict__ ak,
                           float* __restrict__ rdB, float* __restrict__ rdC) {
    int wid = (blockIdx.x * blockDim.x + threadIdx.x) >> 6;
    int lane = threadIdx.x & 63;
    if (wid >= NREL) return;
    float2 v = reinterpret_cast<const float2*>(rel + (size_t)wid * DIM)[lane];
    float2 b = reinterpret_cast<const float2*>(ak + DIM)[lane];
    float2 c = reinterpret_cast<const float2*>(ak + 2 * DIM)[lane];
    float pb = wave_sum(v.x * b.x + v.y * b.y);
    float pc = wave_sum(v.x * c.x + v.y * c.y);
    if (lane == 0) { rdB[wid] = pb; rdC[wid] = pc; }
}

// per-edge normalization scalar: sp_val * rsqrt(max(sp_val^2*||rel||^2, 1e-12))
__global__ void k_scale(const float* __restrict__ sp_val, const int* __restrict__ sp_rel,
                        const float* __restrict__ relnorm2, float* __restrict__ scale) {
    int e = blockIdx.x * blockDim.x + threadIdx.x;
    if (e >= NEDGE) return;
    float v = sp_val[e];
    float n2 = v * v * relnorm2[sp_rel[e]];
    scale[e] = v * rsqrtf(fmaxf(n2, 1e-12f));
}

// CSR row_ptr by binary search over sorted adj_src
__global__ void k_rowptr(const int* __restrict__ adj_src, int* __restrict__ row_ptr) {
    int n = blockIdx.x * blockDim.x + threadIdx.x;
    if (n > NNODE) return;
    int lo = 0, hi = NEDGE;
    while (lo < hi) {
        int mid = (lo + hi) >> 1;
        if (adj_src[mid] < n) lo = mid + 1; else hi = mid;
    }
    row_ptr[n] = lo;
}

// per-node dots with attn kernel parts A (self) and B (neigh)
__global__ void k_node_dots(const float* __restrict__ feats, const float* __restrict__ ak,
                            float* __restrict__ selfdot, float* __restrict__ neighdot) {
    int wid = (blockIdx.x * blockDim.x + threadIdx.x) >> 6;
    int lane = threadIdx.x & 63;
    if (wid >= NNODE) return;
    float2 f = reinterpret_cast<const float2*>(feats + (size_t)wid * OUTC)[lane];
    float2 a = reinterpret_cast<const float2*>(ak)[lane];
    float2 b = reinterpret_cast<const float2*>(ak + DIM)[lane];
    float pa = wave_sum(f.x * a.x + f.y * a.y);
    float pb = wave_sum(f.x * b.x + f.y * b.y);
    if (lane == 0) { selfdot[wid] = pa; neighdot[wid] = pb; }
}

// one wave per node; 4 groups x 16 lanes, each group an independent
// online-softmax state over every 4th edge; flash-merge at the end.
__global__ void k_gat(const float* __restrict__ feats_in, float* __restrict__ feats_out,
                      const float* __restrict__ rel_emb,
                      const int* __restrict__ adj_dst, const int* __restrict__ sp_rel,
                      const float* __restrict__ scale,
                      const float* __restrict__ selfdot, const float* __restrict__ neighdot,
                      const float* __restrict__ rdB, const float* __restrict__ rdC,
                      const int* __restrict__ row_ptr) {
    int wid = (blockIdx.x * blockDim.x + threadIdx.x) >> 6;
    int lane = threadIdx.x & 63;
    if (wid >= NNODE) return;
    int g  = lane >> 4;   // group 0..3
    int gl = lane & 15;   // lane in group; owns dims [gl*8, gl*8+8)
    int e0 = row_ptr[wid], e1 = row_ptr[wid + 1];

    float4 accA = make_float4(0.f, 0.f, 0.f, 0.f);
    float4 accB = make_float4(0.f, 0.f, 0.f, 0.f);
    float m = -3.0e38f, s = 0.f;
    float sd = selfdot[wid];

    for (int e = e0 + g; e < e1; e += 4) {
        int dst = adj_dst[e];
        int r   = sp_rel[e];
        float sc = scale[e];
        const float4* fp = reinterpret_cast<const float4*>(feats_in + (size_t)dst * OUTC) + gl * 2;
        float4 fA = fp[0], fB = fp[1];
        const float4* rp = reinterpret_cast<const float4*>(rel_emb + (size_t)r * DIM) + gl * 2;
        float4 rA = rp[0], rB = rp[1];
        float dot = fA.x * rA.x + fA.y * rA.y + fA.z * rA.z + fA.w * rA.w
                  + fB.x * rB.x + fB.y * rB.y + fB.z * rB.z + fB.w * rB.w;
        dot += __shfl_xor(dot, 1, 64);
        dot += __shfl_xor(dot, 2, 64);
        dot += __shfl_xor(dot, 4, 64);
        dot += __shfl_xor(dot, 8, 64);
        float c = sc * dot;
        float att = sd + neighdot[dst] + sc * (rdC[r] - 2.f * c * rdB[r]);
        float nm = fmaxf(m, att);
        float corr = __expf(m - nm);
        float w = __expf(att - nm);
        s = s * corr + w;
        float k2 = 2.f * c * sc;
        accA.x = accA.x * corr + w * (fA.x - k2 * rA.x);
        accA.y = accA.y * corr + w * (fA.y - k2 * rA.y);
        accA.z = accA.z * corr + w * (fA.z - k2 * rA.z);
        accA.w = accA.w * corr + w * (fA.w - k2 * rA.w);
        accB.x = accB.x * corr + w * (fB.x - k2 * rB.x);
        accB.y = accB.y * corr + w * (fB.y - k2 * rB.y);
        accB.z = accB.z * corr + w * (fB.z - k2 * rB.z);
        accB.w = accB.w * corr + w * (fB.w - k2 * rB.w);
        m = nm;
    }

    // flash-merge the 4 group states (lanes differing in bits 4,5)
#pragma unroll
    for (int off = 16; off <= 32; off <<= 1) {
        float mo = __shfl_xor(m, off, 64);
        float so = __shfl_xor(s, off, 64);
        float4 oA, oB;
        oA.x = __shfl_xor(accA.x, off, 64);
        oA.y = __shfl_xor(accA.y, off, 64);
        oA.z = __shfl_xor(accA.z, off, 64);
        oA.w = __shfl_xor(accA.w, off, 64);
        oB.x = __shfl_xor(accB.x, off, 64);
        oB.y = __shfl_xor(accB.y, off, 64);
        oB.z = __shfl_xor(accB.z, off, 64);
        oB.w = __shfl_xor(accB.w, off, 64);
        float nm = fmaxf(m, mo);
        float wa = __expf(m - nm), wb = __expf(mo - nm);
        s = s * wa + so * wb;
        accA.x = accA.x * wa + oA.x * wb;
        accA.y = accA.y * wa + oA.y * wb;
        accA.z = accA.z * wa + oA.z * wb;
        accA.w = accA.w * wa + oA.w * wb;
        accB.x = accB.x * wa + oB.x * wb;
        accB.y = accB.y * wa + oB.y * wb;
        accB.z = accB.z * wa + oB.z * wb;
        accB.w = accB.w * wa + oB.w * wb;
        m = nm;
    }

    if (g == 0) {
        float4 oA = make_float4(0.f, 0.f, 0.f, 0.f);
        float4 oB = make_float4(0.f, 0.f, 0.f, 0.f);
        if (s > 0.f) {
            float inv = 1.f / s;
            oA.x = fmaxf(accA.x * inv, 0.f);
            oA.y = fmaxf(accA.y * inv, 0.f);
            oA.z = fmaxf(accA.z * inv, 0.f);
            oA.w = fmaxf(accA.w * inv, 0.f);
            oB.x = fmaxf(accB.x * inv, 0.f);
            oB.y = fmaxf(accB.y * inv, 0.f);
            oB.z = fmaxf(accB.z * inv, 0.f);
            oB.w = fmaxf(accB.w * inv, 0.f);
        }
        float4* op = reinterpret_cast<float4*>(feats_out + (size_t)wid * OUTC) + gl * 2;
        op[0] = oA;
        op[1] = oB;
    }
}

extern "C" void kernel_launch(void* const* d_in, const int* in_sizes, int n_in,
                              void* d_out, int out_size, void* d_ws, size_t ws_size,
                              hipStream_t stream) {
    const float* features = (const float*)d_in[0];
    const float* rel_emb  = (const float*)d_in[1];
    const float* sp_val   = (const float*)d_in[2];
    const float* attn     = (const float*)d_in[3];
    const int*   adj_src  = (const int*)d_in[4];
    const int*   adj_dst  = (const int*)d_in[5];
    const int*   sp_rel   = (const int*)d_in[6];
    // d_in[7] = sp_row = arange(E) -> identity segment_sum, unused
    float* out = (float*)d_out;

    char* ws = (char*)d_ws;
    float* scale    = (float*)ws; ws += (size_t)NEDGE * sizeof(float);
    float* selfdot  = (float*)ws; ws += (size_t)NNODE * sizeof(float);
    float* neighdot = (float*)ws; ws += (size_t)NNODE * sizeof(float);
    float* relnorm2 = (float*)ws; ws += (size_t)NREL * sizeof(float);
    float* rdB      = (float*)ws; ws += (size_t)NREL * sizeof(float);
    float* rdC      = (float*)ws; ws += (size_t)NREL * sizeof(float);
    int*   row_ptr  = (int*)ws;   ws += (size_t)(NNODE + 1) * sizeof(int);

    k_relu_in<<<(NNODE * 32 + 255) / 256, 256, 0, stream>>>(features, out);
    k_rel_norm<<<(NREL * 64 + 255) / 256, 256, 0, stream>>>(rel_emb, relnorm2);
    k_scale<<<(NEDGE + 255) / 256, 256, 0, stream>>>(sp_val, sp_rel, relnorm2, scale);
    k_rowptr<<<(NNODE + 1 + 255) / 256, 256, 0, stream>>>(adj_src, row_ptr);

    for (int l = 0; l < NDEPTH; ++l) {
        const float* ak  = attn + (size_t)l * 3 * DIM;
        const float* fin = out + (size_t)l * DIM;
        float*       fout = out + (size_t)(l + 1) * DIM;
        k_rel_dots<<<(NREL * 64 + 255) / 256, 256, 0, stream>>>(rel_emb, ak, rdB, rdC);
        k_node_dots<<<(NNODE * 64 + 255) / 256, 256, 0, stream>>>(fin, ak, selfdot, neighdot);
        k_gat<<<(NNODE * 64 + 255) / 256, 256, 0, stream>>>(fin, fout, rel_emb, adj_dst, sp_rel,
                                                            scale, selfdot, neighdot, rdB, rdC, row_ptr);
    }
}

// Round 3
// 190.002 us; speedup vs baseline: 1.4476x; 1.1924x over previous
//
#include <hip/hip_runtime.h>
#include <math.h>

#define NNODE 100000
#define NREL 2000
#define NEDGE 600000
#define DIM 128
#define NDEPTH 2
#define OUTC 384   // DIM*(DEPTH+1)

__device__ __forceinline__ float wave_sum(float v) {
#pragma unroll
    for (int off = 32; off > 0; off >>= 1)
        v += __shfl_xor(v, off, 64);
    return v;
}

// round-to-nearest-even f32 -> bf16 bits
__device__ __forceinline__ unsigned short f2bf(float f) {
    unsigned b = __float_as_uint(f);
    return (unsigned short)((b + 0x7fffu + ((b >> 16) & 1u)) >> 16);
}
__device__ __forceinline__ unsigned pack2(float f0, float f1) {
    return (unsigned)f2bf(f0) | ((unsigned)f2bf(f1) << 16);
}
__device__ __forceinline__ void unpack2(unsigned u, float& lo, float& hi) {
    lo = __uint_as_float(u << 16);
    hi = __uint_as_float(u & 0xffff0000u);
}

// relu(features) -> d_out cols [0,128) (f32) + bf16 mirror
__global__ void k_relu_in(const float* __restrict__ f, float* __restrict__ out,
                          unsigned short* __restrict__ fm) {
    int idx = blockIdx.x * blockDim.x + threadIdx.x;
    if (idx >= NNODE * 32) return;
    int n = idx >> 5;   // 32 float4 per row
    int q = idx & 31;
    float4 v = reinterpret_cast<const float4*>(f + (size_t)n * DIM)[q];
    v.x = fmaxf(v.x, 0.f); v.y = fmaxf(v.y, 0.f);
    v.z = fmaxf(v.z, 0.f); v.w = fmaxf(v.w, 0.f);
    reinterpret_cast<float4*>(out + (size_t)n * OUTC)[q] = v;
    uint2 p;
    p.x = pack2(v.x, v.y);
    p.y = pack2(v.z, v.w);
    reinterpret_cast<uint2*>(fm + (size_t)n * DIM)[q] = p;
}

// per-relation: ||rel||^2, rdB/rdC for BOTH layers, bf16 mirror of rel_emb
__global__ void k_pre(const float* __restrict__ rel, const float* __restrict__ attn,
                      float* __restrict__ relnorm2, float* __restrict__ rdB,
                      float* __restrict__ rdC, unsigned short* __restrict__ relm) {
    int wid = (blockIdx.x * blockDim.x + threadIdx.x) >> 6;
    int lane = threadIdx.x & 63;
    if (wid >= NREL) return;
    float2 v = reinterpret_cast<const float2*>(rel + (size_t)wid * DIM)[lane];
    reinterpret_cast<unsigned*>(relm + (size_t)wid * DIM)[lane] = pack2(v.x, v.y);
    float2 b0 = reinterpret_cast<const float2*>(attn + DIM)[lane];
    float2 c0 = reinterpret_cast<const float2*>(attn + 2 * DIM)[lane];
    float2 b1 = reinterpret_cast<const float2*>(attn + 3 * DIM + DIM)[lane];
    float2 c1 = reinterpret_cast<const float2*>(attn + 3 * DIM + 2 * DIM)[lane];
    float n2  = wave_sum(v.x * v.x + v.y * v.y);
    float pb0 = wave_sum(v.x * b0.x + v.y * b0.y);
    float pc0 = wave_sum(v.x * c0.x + v.y * c0.y);
    float pb1 = wave_sum(v.x * b1.x + v.y * b1.y);
    float pc1 = wave_sum(v.x * c1.x + v.y * c1.y);
    if (lane == 0) {
        relnorm2[wid] = n2;
        rdB[wid] = pb0;        rdC[wid] = pc0;
        rdB[NREL + wid] = pb1; rdC[NREL + wid] = pc1;
    }
}

// fused: per-edge scale + CSR row_ptr (binary search over sorted adj_src)
__global__ void k_scale_rowptr(const float* __restrict__ sp_val, const int* __restrict__ sp_rel,
                               const float* __restrict__ relnorm2, float* __restrict__ scale,
                               const int* __restrict__ adj_src, int* __restrict__ row_ptr) {
    int i = blockIdx.x * blockDim.x + threadIdx.x;
    if (i < NEDGE) {
        float v = sp_val[i];
        float n2 = v * v * relnorm2[sp_rel[i]];
        scale[i] = v * rsqrtf(fmaxf(n2, 1e-12f));
    }
    int n = i - NEDGE;
    if (n >= 0 && n <= NNODE) {
        int lo = 0, hi = NEDGE;
        while (lo < hi) {
            int mid = (lo + hi) >> 1;
            if (adj_src[mid] < n) lo = mid + 1; else hi = mid;
        }
        row_ptr[n] = lo;
    }
}

// per-node dots with attn kernel parts A (self) and B (neigh), from bf16 mirror
__global__ void k_node_dots(const unsigned short* __restrict__ fm, const float* __restrict__ ak,
                            float* __restrict__ selfdot, float* __restrict__ neighdot) {
    int wid = (blockIdx.x * blockDim.x + threadIdx.x) >> 6;
    int lane = threadIdx.x & 63;
    if (wid >= NNODE) return;
    unsigned u = reinterpret_cast<const unsigned*>(fm + (size_t)wid * DIM)[lane];
    float f0, f1; unpack2(u, f0, f1);
    float2 a = reinterpret_cast<const float2*>(ak)[lane];
    float2 b = reinterpret_cast<const float2*>(ak + DIM)[lane];
    float pa = wave_sum(f0 * a.x + f1 * a.y);
    float pb = wave_sum(f0 * b.x + f1 * b.y);
    if (lane == 0) { selfdot[wid] = pa; neighdot[wid] = pb; }
}

// one wave per node; 4 groups x 16 lanes, independent online-softmax states over
// strided edges with 1-deep prefetch; flash-merge; writes f32 slice + bf16 mirror.
__global__ void k_gat(const unsigned short* __restrict__ fin_m,
                      float* __restrict__ fout,
                      unsigned short* __restrict__ fout_m,
                      const unsigned short* __restrict__ relm,
                      const int* __restrict__ adj_dst, const int* __restrict__ sp_rel,
                      const float* __restrict__ scale,
                      const float* __restrict__ selfdot, const float* __restrict__ neighdot,
                      const float* __restrict__ rdB, const float* __restrict__ rdC,
                      const int* __restrict__ row_ptr, const int write_mirror) {
    int wid = (blockIdx.x * blockDim.x + threadIdx.x) >> 6;
    int lane = threadIdx.x & 63;
    if (wid >= NNODE) return;
    int g  = lane >> 4;   // group 0..3
    int gl = lane & 15;   // owns dims [gl*8, gl*8+8)
    int e0 = row_ptr[wid], e1 = row_ptr[wid + 1];

    float acc[8];
#pragma unroll
    for (int i = 0; i < 8; ++i) acc[i] = 0.f;
    float m = -3.0e38f, s = 0.f;
    float sd = selfdot[wid];

    int e = e0 + g;
    uint4 fb = make_uint4(0, 0, 0, 0), rb = make_uint4(0, 0, 0, 0);
    float ab = 0.f, qb = 0.f, q2 = 0.f;
    if (e < e1) {
        int dst = adj_dst[e], r = sp_rel[e];
        float sc = scale[e];
        fb = reinterpret_cast<const uint4*>(fin_m + (size_t)dst * DIM)[gl];
        rb = reinterpret_cast<const uint4*>(relm + (size_t)r * DIM)[gl];
        float s2 = 2.f * sc * sc;
        ab = neighdot[dst] + sc * rdC[r];
        qb = s2 * rdB[r];
        q2 = s2;
    }
    while (e < e1) {
        int en = e + 4;
        uint4 fb2 = make_uint4(0, 0, 0, 0), rb2 = make_uint4(0, 0, 0, 0);
        float ab2 = 0.f, qb2 = 0.f, q22 = 0.f;
        if (en < e1) {   // prefetch next edge before current's dependent chain
            int dst = adj_dst[en], r = sp_rel[en];
            float sc = scale[en];
            fb2 = reinterpret_cast<const uint4*>(fin_m + (size_t)dst * DIM)[gl];
            rb2 = reinterpret_cast<const uint4*>(relm + (size_t)r * DIM)[gl];
            float s2 = 2.f * sc * sc;
            ab2 = neighdot[dst] + sc * rdC[r];
            qb2 = s2 * rdB[r];
            q22 = s2;
        }
        float f[8], rv[8];
        unpack2(fb.x, f[0], f[1]); unpack2(fb.y, f[2], f[3]);
        unpack2(fb.z, f[4], f[5]); unpack2(fb.w, f[6], f[7]);
        unpack2(rb.x, rv[0], rv[1]); unpack2(rb.y, rv[2], rv[3]);
        unpack2(rb.z, rv[4], rv[5]); unpack2(rb.w, rv[6], rv[7]);
        float dot = 0.f;
#pragma unroll
        for (int i = 0; i < 8; ++i) dot += f[i] * rv[i];
        dot += __shfl_xor(dot, 1, 64);
        dot += __shfl_xor(dot, 2, 64);
        dot += __shfl_xor(dot, 4, 64);
        dot += __shfl_xor(dot, 8, 64);
        float att = sd + ab - dot * qb;
        float k2 = dot * q2;
        float nm = fmaxf(m, att);
        float corr = __expf(m - nm);
        float w = __expf(att - nm);
        s = s * corr + w;
#pragma unroll
        for (int i = 0; i < 8; ++i)
            acc[i] = acc[i] * corr + w * (f[i] - k2 * rv[i]);
        m = nm;
        e = en; fb = fb2; rb = rb2; ab = ab2; qb = qb2; q2 = q22;
    }

    // flash-merge the 4 group states
#pragma unroll
    for (int off = 16; off <= 32; off <<= 1) {
        float mo = __shfl_xor(m, off, 64);
        float so = __shfl_xor(s, off, 64);
        float ao[8];
#pragma unroll
        for (int i = 0; i < 8; ++i) ao[i] = __shfl_xor(acc[i], off, 64);
        float nm = fmaxf(m, mo);
        float wa = __expf(m - nm), wb = __expf(mo - nm);
        s = s * wa + so * wb;
#pragma unroll
        for (int i = 0; i < 8; ++i) acc[i] = acc[i] * wa + ao[i] * wb;
        m = nm;
    }

    if (g == 0) {
        float inv = (s > 0.f) ? 1.f / s : 0.f;
        float o[8];
#pragma unroll
        for (int i = 0; i < 8; ++i) o[i] = fmaxf(acc[i] * inv, 0.f);
        float4* op = reinterpret_cast<float4*>(fout + (size_t)wid * OUTC) + gl * 2;
        op[0] = make_float4(o[0], o[1], o[2], o[3]);
        op[1] = make_float4(o[4], o[5], o[6], o[7]);
        if (write_mirror) {
            uint4 mw;
            mw.x = pack2(o[0], o[1]); mw.y = pack2(o[2], o[3]);
            mw.z = pack2(o[4], o[5]); mw.w = pack2(o[6], o[7]);
            reinterpret_cast<uint4*>(fout_m + (size_t)wid * DIM)[gl] = mw;
        }
    }
}

extern "C" void kernel_launch(void* const* d_in, const int* in_sizes, int n_in,
                              void* d_out, int out_size, void* d_ws, size_t ws_size,
                              hipStream_t stream) {
    const float* features = (const float*)d_in[0];
    const float* rel_emb  = (const float*)d_in[1];
    const float* sp_val   = (const float*)d_in[2];
    const float* attn     = (const float*)d_in[3];
    const int*   adj_src  = (const int*)d_in[4];
    const int*   adj_dst  = (const int*)d_in[5];
    const int*   sp_rel   = (const int*)d_in[6];
    // d_in[7] = sp_row = arange(E) -> identity segment_sum, unused
    float* out = (float*)d_out;

    char* p = (char*)d_ws;
    unsigned short* mir0 = (unsigned short*)p; p += (size_t)NNODE * DIM * 2;
    unsigned short* mir1 = (unsigned short*)p; p += (size_t)NNODE * DIM * 2;
    unsigned short* relm = (unsigned short*)p; p += (size_t)NREL * DIM * 2;
    float* scale    = (float*)p; p += (size_t)NEDGE * 4;
    float* selfdot  = (float*)p; p += (size_t)NNODE * 4;
    float* neighdot = (float*)p; p += (size_t)NNODE * 4;
    float* relnorm2 = (float*)p; p += (size_t)NREL * 4;
    float* rdB      = (float*)p; p += (size_t)2 * NREL * 4;
    float* rdC      = (float*)p; p += (size_t)2 * NREL * 4;
    int*   row_ptr  = (int*)p;   p += (size_t)(NNODE + 1) * 4;

    k_pre<<<(NREL * 64 + 255) / 256, 256, 0, stream>>>(rel_emb, attn, relnorm2, rdB, rdC, relm);
    k_relu_in<<<(NNODE * 32 + 255) / 256, 256, 0, stream>>>(features, out, mir0);
    k_scale_rowptr<<<(NEDGE + NNODE + 1 + 255) / 256, 256, 0, stream>>>(
        sp_val, sp_rel, relnorm2, scale, adj_src, row_ptr);

    const unsigned short* mirs[2] = {mir0, mir1};
    for (int l = 0; l < NDEPTH; ++l) {
        const float* ak = attn + (size_t)l * 3 * DIM;
        float* fout = out + (size_t)(l + 1) * DIM;
        k_node_dots<<<(NNODE * 64 + 255) / 256, 256, 0, stream>>>(mirs[l], ak, selfdot, neighdot);
        k_gat<<<(NNODE * 64 + 255) / 256, 256, 0, stream>>>(
            mirs[l], fout, (l == 0) ? mir1 : (unsigned short*)nullptr, relm,
            adj_dst, sp_rel, scale, selfdot, neighdot,
            rdB + (size_t)l * NREL, rdC + (size_t)l * NREL, row_ptr, (l == 0) ? 1 : 0);
    }
}

// Round 4
// 163.171 us; speedup vs baseline: 1.6857x; 1.1644x over previous
//
#include <hip/hip_runtime.h>
#include <math.h>

#define NNODE 100000
#define NREL 2000
#define NEDGE 600000
#define DIM 128
#define NDEPTH 2
#define OUTC 384   // DIM*(DEPTH+1)

#define RELU_BLOCKS 12500                      // NNODE*32/256
#define PRE_BLOCKS 500                         // NREL*64/256
#define ROW_BLOCKS ((NNODE + 1 + 255) / 256)   // 391

__device__ __forceinline__ float wave_sum(float v) {
#pragma unroll
    for (int off = 32; off > 0; off >>= 1)
        v += __shfl_xor(v, off, 64);
    return v;
}

// round-to-nearest-even f32 -> bf16 bits
__device__ __forceinline__ unsigned short f2bf(float f) {
    unsigned b = __float_as_uint(f);
    return (unsigned short)((b + 0x7fffu + ((b >> 16) & 1u)) >> 16);
}
__device__ __forceinline__ unsigned pack2(float f0, float f1) {
    return (unsigned)f2bf(f0) | ((unsigned)f2bf(f1) << 16);
}
__device__ __forceinline__ void unpack2(unsigned u, float& lo, float& hi) {
    lo = __uint_as_float(u << 16);
    hi = __uint_as_float(u & 0xffff0000u);
}

// Fused setup, region-partitioned by blockIdx:
//  [0, RELU_BLOCKS)           relu(features) -> d_out f32 + bf16 mirror + layer-0 self/neigh dots
//  [.., +PRE_BLOCKS)          per-relation ||rel||^2, rdB/rdC both layers, rel bf16 mirror
//  [.., +ROW_BLOCKS)          CSR row_ptr by binary search over sorted adj_src
__global__ void k_setup(const float* __restrict__ f, const float* __restrict__ rel,
                        const float* __restrict__ attn, const int* __restrict__ adj_src,
                        float* __restrict__ out, unsigned short* __restrict__ fm,
                        unsigned short* __restrict__ relm,
                        float* __restrict__ relnorm2, float* __restrict__ rdB,
                        float* __restrict__ rdC,
                        float* __restrict__ selfdot0, float* __restrict__ neighdot0,
                        int* __restrict__ row_ptr) {
    int b = blockIdx.x;
    if (b < RELU_BLOCKS) {
        int idx = b * 256 + threadIdx.x;
        int n = idx >> 5;   // 32 float4 per row
        int q = idx & 31;
        float4 v = reinterpret_cast<const float4*>(f + (size_t)n * DIM)[q];
        v.x = fmaxf(v.x, 0.f); v.y = fmaxf(v.y, 0.f);
        v.z = fmaxf(v.z, 0.f); v.w = fmaxf(v.w, 0.f);
        reinterpret_cast<float4*>(out + (size_t)n * OUTC)[q] = v;
        uint2 p;
        p.x = pack2(v.x, v.y);
        p.y = pack2(v.z, v.w);
        reinterpret_cast<uint2*>(fm + (size_t)n * DIM)[q] = p;
        // layer-0 per-node dots with attn parts A and B
        float4 a = reinterpret_cast<const float4*>(attn)[q];
        float4 bb = reinterpret_cast<const float4*>(attn + DIM)[q];
        float pa = v.x * a.x + v.y * a.y + v.z * a.z + v.w * a.w;
        float pb = v.x * bb.x + v.y * bb.y + v.z * bb.z + v.w * bb.w;
#pragma unroll
        for (int off = 1; off <= 16; off <<= 1) {
            pa += __shfl_xor(pa, off, 64);
            pb += __shfl_xor(pb, off, 64);
        }
        if (q == 0) { selfdot0[n] = pa; neighdot0[n] = pb; }
    } else if (b < RELU_BLOCKS + PRE_BLOCKS) {
        int wid = (b - RELU_BLOCKS) * 4 + (threadIdx.x >> 6);  // < NREL exactly
        int lane = threadIdx.x & 63;
        float2 v = reinterpret_cast<const float2*>(rel + (size_t)wid * DIM)[lane];
        reinterpret_cast<unsigned*>(relm + (size_t)wid * DIM)[lane] = pack2(v.x, v.y);
        float2 b0 = reinterpret_cast<const float2*>(attn + DIM)[lane];
        float2 c0 = reinterpret_cast<const float2*>(attn + 2 * DIM)[lane];
        float2 b1 = reinterpret_cast<const float2*>(attn + 3 * DIM + DIM)[lane];
        float2 c1 = reinterpret_cast<const float2*>(attn + 3 * DIM + 2 * DIM)[lane];
        float n2  = wave_sum(v.x * v.x + v.y * v.y);
        float pb0 = wave_sum(v.x * b0.x + v.y * b0.y);
        float pc0 = wave_sum(v.x * c0.x + v.y * c0.y);
        float pb1 = wave_sum(v.x * b1.x + v.y * b1.y);
        float pc1 = wave_sum(v.x * c1.x + v.y * c1.y);
        if (lane == 0) {
            relnorm2[wid] = n2;
            rdB[wid] = pb0;        rdC[wid] = pc0;
            rdB[NREL + wid] = pb1; rdC[NREL + wid] = pc1;
        }
    } else {
        int n = (b - RELU_BLOCKS - PRE_BLOCKS) * 256 + threadIdx.x;
        if (n <= NNODE) {
            int lo = 0, hi = NEDGE;
            while (lo < hi) {
                int mid = (lo + hi) >> 1;
                if (adj_src[mid] < n) lo = mid + 1; else hi = mid;
            }
            row_ptr[n] = lo;
        }
    }
}

// one wave per node; 4 groups x 16 lanes, independent online-softmax states over
// strided edges with 1-deep prefetch and inline scale; flash-merge; epilogue writes
// f32 slice (+ bf16 mirror and next-layer self/neigh dots when write_next).
__global__ void k_gat(const unsigned short* __restrict__ fin_m,
                      float* __restrict__ fout,
                      unsigned short* __restrict__ fout_m,
                      const unsigned short* __restrict__ relm,
                      const int* __restrict__ adj_dst, const int* __restrict__ sp_rel,
                      const float* __restrict__ sp_val, const float* __restrict__ relnorm2,
                      const float* __restrict__ selfdot, const float* __restrict__ neighdot,
                      const float* __restrict__ rdB, const float* __restrict__ rdC,
                      const int* __restrict__ row_ptr,
                      float* __restrict__ selfdot_n, float* __restrict__ neighdot_n,
                      const float* __restrict__ ak_next, const int write_next) {
    int wid = (blockIdx.x * blockDim.x + threadIdx.x) >> 6;
    int lane = threadIdx.x & 63;
    if (wid >= NNODE) return;
    int g  = lane >> 4;   // group 0..3
    int gl = lane & 15;   // owns dims [gl*8, gl*8+8)
    int e0 = row_ptr[wid], e1 = row_ptr[wid + 1];

    float acc[8];
#pragma unroll
    for (int i = 0; i < 8; ++i) acc[i] = 0.f;
    float m = -3.0e38f, s = 0.f;
    float sd = selfdot[wid];

    int e = e0 + g;
    uint4 fb = make_uint4(0, 0, 0, 0), rb = make_uint4(0, 0, 0, 0);
    float ab = 0.f, qb = 0.f, q2 = 0.f;
    if (e < e1) {
        int dst = adj_dst[e], r = sp_rel[e];
        float v = sp_val[e];
        float sc = v * rsqrtf(fmaxf(v * v * relnorm2[r], 1e-12f));
        fb = reinterpret_cast<const uint4*>(fin_m + (size_t)dst * DIM)[gl];
        rb = reinterpret_cast<const uint4*>(relm + (size_t)r * DIM)[gl];
        float s2 = 2.f * sc * sc;
        ab = neighdot[dst] + sc * rdC[r];
        qb = s2 * rdB[r];
        q2 = s2;
    }
    while (e < e1) {
        int en = e + 4;
        uint4 fb2 = make_uint4(0, 0, 0, 0), rb2 = make_uint4(0, 0, 0, 0);
        float ab2 = 0.f, qb2 = 0.f, q22 = 0.f;
        if (en < e1) {   // prefetch next edge before current's dependent chain
            int dst = adj_dst[en], r = sp_rel[en];
            float v = sp_val[en];
            float sc = v * rsqrtf(fmaxf(v * v * relnorm2[r], 1e-12f));
            fb2 = reinterpret_cast<const uint4*>(fin_m + (size_t)dst * DIM)[gl];
            rb2 = reinterpret_cast<const uint4*>(relm + (size_t)r * DIM)[gl];
            float s2 = 2.f * sc * sc;
            ab2 = neighdot[dst] + sc * rdC[r];
            qb2 = s2 * rdB[r];
            q22 = s2;
        }
        float f[8], rv[8];
        unpack2(fb.x, f[0], f[1]); unpack2(fb.y, f[2], f[3]);
        unpack2(fb.z, f[4], f[5]); unpack2(fb.w, f[6], f[7]);
        unpack2(rb.x, rv[0], rv[1]); unpack2(rb.y, rv[2], rv[3]);
        unpack2(rb.z, rv[4], rv[5]); unpack2(rb.w, rv[6], rv[7]);
        float dot = 0.f;
#pragma unroll
        for (int i = 0; i < 8; ++i) dot += f[i] * rv[i];
        dot += __shfl_xor(dot, 1, 64);
        dot += __shfl_xor(dot, 2, 64);
        dot += __shfl_xor(dot, 4, 64);
        dot += __shfl_xor(dot, 8, 64);
        float att = sd + ab - dot * qb;
        float k2 = dot * q2;
        float nm = fmaxf(m, att);
        float corr = __expf(m - nm);
        float w = __expf(att - nm);
        s = s * corr + w;
#pragma unroll
        for (int i = 0; i < 8; ++i)
            acc[i] = acc[i] * corr + w * (f[i] - k2 * rv[i]);
        m = nm;
        e = en; fb = fb2; rb = rb2; ab = ab2; qb = qb2; q2 = q22;
    }

    // flash-merge the 4 group states
#pragma unroll
    for (int off = 16; off <= 32; off <<= 1) {
        float mo = __shfl_xor(m, off, 64);
        float so = __shfl_xor(s, off, 64);
        float ao[8];
#pragma unroll
        for (int i = 0; i < 8; ++i) ao[i] = __shfl_xor(acc[i], off, 64);
        float nm = fmaxf(m, mo);
        float wa = __expf(m - nm), wb = __expf(mo - nm);
        s = s * wa + so * wb;
#pragma unroll
        for (int i = 0; i < 8; ++i) acc[i] = acc[i] * wa + ao[i] * wb;
        m = nm;
    }

    if (g == 0) {
        float inv = (s > 0.f) ? 1.f / s : 0.f;
        float o[8];
#pragma unroll
        for (int i = 0; i < 8; ++i) o[i] = fmaxf(acc[i] * inv, 0.f);
        float4* op = reinterpret_cast<float4*>(fout + (size_t)wid * OUTC) + gl * 2;
        op[0] = make_float4(o[0], o[1], o[2], o[3]);
        op[1] = make_float4(o[4], o[5], o[6], o[7]);
        if (write_next) {
            uint4 mw;
            mw.x = pack2(o[0], o[1]); mw.y = pack2(o[2], o[3]);
            mw.z = pack2(o[4], o[5]); mw.w = pack2(o[6], o[7]);
            reinterpret_cast<uint4*>(fout_m + (size_t)wid * DIM)[gl] = mw;
            // next-layer per-node dots from the fresh output (16-lane reduce)
            const float4* aA = reinterpret_cast<const float4*>(ak_next) + gl * 2;
            const float4* aB = reinterpret_cast<const float4*>(ak_next + DIM) + gl * 2;
            float4 a0 = aA[0], a1 = aA[1], b0 = aB[0], b1 = aB[1];
            float pa = o[0] * a0.x + o[1] * a0.y + o[2] * a0.z + o[3] * a0.w
                     + o[4] * a1.x + o[5] * a1.y + o[6] * a1.z + o[7] * a1.w;
            float pb = o[0] * b0.x + o[1] * b0.y + o[2] * b0.z + o[3] * b0.w
                     + o[4] * b1.x + o[5] * b1.y + o[6] * b1.z + o[7] * b1.w;
#pragma unroll
            for (int off = 1; off <= 8; off <<= 1) {
                pa += __shfl_xor(pa, off, 64);
                pb += __shfl_xor(pb, off, 64);
            }
            if (gl == 0) { selfdot_n[wid] = pa; neighdot_n[wid] = pb; }
        }
    }
}

extern "C" void kernel_launch(void* const* d_in, const int* in_sizes, int n_in,
                              void* d_out, int out_size, void* d_ws, size_t ws_size,
                              hipStream_t stream) {
    const float* features = (const float*)d_in[0];
    const float* rel_emb  = (const float*)d_in[1];
    const float* sp_val   = (const float*)d_in[2];
    const float* attn     = (const float*)d_in[3];
    const int*   adj_src  = (const int*)d_in[4];
    const int*   adj_dst  = (const int*)d_in[5];
    const int*   sp_rel   = (const int*)d_in[6];
    // d_in[7] = sp_row = arange(E) -> identity segment_sum, unused
    float* out = (float*)d_out;

    char* p = (char*)d_ws;
    unsigned short* mir0 = (unsigned short*)p; p += (size_t)NNODE * DIM * 2;
    unsigned short* mir1 = (unsigned short*)p; p += (size_t)NNODE * DIM * 2;
    unsigned short* relm = (unsigned short*)p; p += (size_t)NREL * DIM * 2;
    float* sd0      = (float*)p; p += (size_t)NNODE * 4;
    float* nd0      = (float*)p; p += (size_t)NNODE * 4;
    float* sd1      = (float*)p; p += (size_t)NNODE * 4;
    float* nd1      = (float*)p; p += (size_t)NNODE * 4;
    float* relnorm2 = (float*)p; p += (size_t)NREL * 4;
    float* rdB      = (float*)p; p += (size_t)2 * NREL * 4;
    float* rdC      = (float*)p; p += (size_t)2 * NREL * 4;
    int*   row_ptr  = (int*)p;   p += (size_t)(NNODE + 1) * 4;

    k_setup<<<RELU_BLOCKS + PRE_BLOCKS + ROW_BLOCKS, 256, 0, stream>>>(
        features, rel_emb, attn, adj_src, out, mir0, relm,
        relnorm2, rdB, rdC, sd0, nd0, row_ptr);

    k_gat<<<(NNODE * 64 + 255) / 256, 256, 0, stream>>>(
        mir0, out + DIM, mir1, relm, adj_dst, sp_rel, sp_val, relnorm2,
        sd0, nd0, rdB, rdC, row_ptr, sd1, nd1, attn + 3 * DIM, 1);

    k_gat<<<(NNODE * 64 + 255) / 256, 256, 0, stream>>>(
        mir1, out + 2 * DIM, (unsigned short*)nullptr, relm, adj_dst, sp_rel, sp_val, relnorm2,
        sd1, nd1, rdB + NREL, rdC + NREL, row_ptr,
        (float*)nullptr, (float*)nullptr, (const float*)nullptr, 0);
}

// Round 5
// 144.283 us; speedup vs baseline: 1.9063x; 1.1309x over previous
//
#include <hip/hip_runtime.h>
#include <math.h>
#include <stdint.h>

#define NNODE 100000
#define NREL 2000
#define NEDGE 600000
#define DIM 128
#define OUTC 384   // DIM*(DEPTH+1)

#define RELU_BLOCKS 12500                      // NNODE*32/256
#define PRE_BLOCKS 500                         // NREL*64/256
#define ROW_BLOCKS ((NNODE + 1 + 255) / 256)   // 391

typedef float f32x2 __attribute__((ext_vector_type(2)));

__device__ __forceinline__ float wave_sum(float v) {
#pragma unroll
    for (int off = 32; off > 0; off >>= 1)
        v += __shfl_xor(v, off, 64);
    return v;
}

// round-to-nearest-even f32 -> bf16 bits
__device__ __forceinline__ unsigned short f2bf(float f) {
    unsigned b = __float_as_uint(f);
    return (unsigned short)((b + 0x7fffu + ((b >> 16) & 1u)) >> 16);
}
__device__ __forceinline__ unsigned pack2(float f0, float f1) {
    return (unsigned)f2bf(f0) | ((unsigned)f2bf(f1) << 16);
}
// one packed dword (2 bf16) -> f32x2 {lo, hi}
__device__ __forceinline__ f32x2 bf2(unsigned u) {
    f32x2 r;
    r.x = __uint_as_float(u << 16);
    r.y = __uint_as_float(u & 0xffff0000u);
    return r;
}

// Fused setup, region-partitioned by blockIdx:
//  [0, RELU_BLOCKS)      relu(features) -> d_out f32 + bf16 mirror + layer-0 self/neigh dots
//  [.., +PRE_BLOCKS)     per-relation ||rel||^2, rdB/rdC both layers, rel bf16 mirror
//  [.., +ROW_BLOCKS)     CSR row_ptr by binary search over sorted adj_src
__global__ void k_setup(const float* __restrict__ f, const float* __restrict__ rel,
                        const float* __restrict__ attn, const int* __restrict__ adj_src,
                        float* __restrict__ out, unsigned short* __restrict__ fm,
                        unsigned short* __restrict__ relm,
                        float* __restrict__ relnorm2, float* __restrict__ rdB,
                        float* __restrict__ rdC,
                        float* __restrict__ selfdot0, float* __restrict__ neighdot0,
                        int* __restrict__ row_ptr) {
    int b = blockIdx.x;
    if (b < RELU_BLOCKS) {
        int idx = b * 256 + threadIdx.x;
        int n = idx >> 5;   // 32 float4 per row
        int q = idx & 31;
        float4 v = reinterpret_cast<const float4*>(f + (size_t)n * DIM)[q];
        v.x = fmaxf(v.x, 0.f); v.y = fmaxf(v.y, 0.f);
        v.z = fmaxf(v.z, 0.f); v.w = fmaxf(v.w, 0.f);
        reinterpret_cast<float4*>(out + (size_t)n * OUTC)[q] = v;
        uint2 p;
        p.x = pack2(v.x, v.y);
        p.y = pack2(v.z, v.w);
        reinterpret_cast<uint2*>(fm + (size_t)n * DIM)[q] = p;
        // layer-0 per-node dots with attn parts A and B (32-lane segmented reduce)
        float4 a = reinterpret_cast<const float4*>(attn)[q];
        float4 bb = reinterpret_cast<const float4*>(attn + DIM)[q];
        float pa = v.x * a.x + v.y * a.y + v.z * a.z + v.w * a.w;
        float pb = v.x * bb.x + v.y * bb.y + v.z * bb.z + v.w * bb.w;
#pragma unroll
        for (int off = 1; off <= 16; off <<= 1) {
            pa += __shfl_xor(pa, off, 64);
            pb += __shfl_xor(pb, off, 64);
        }
        if (q == 0) { selfdot0[n] = pa; neighdot0[n] = pb; }
    } else if (b < RELU_BLOCKS + PRE_BLOCKS) {
        int wid = (b - RELU_BLOCKS) * 4 + (threadIdx.x >> 6);  // < NREL exactly
        int lane = threadIdx.x & 63;
        float2 v = reinterpret_cast<const float2*>(rel + (size_t)wid * DIM)[lane];
        reinterpret_cast<unsigned*>(relm + (size_t)wid * DIM)[lane] = pack2(v.x, v.y);
        float2 b0 = reinterpret_cast<const float2*>(attn + DIM)[lane];
        float2 c0 = reinterpret_cast<const float2*>(attn + 2 * DIM)[lane];
        float2 b1 = reinterpret_cast<const float2*>(attn + 3 * DIM + DIM)[lane];
        float2 c1 = reinterpret_cast<const float2*>(attn + 3 * DIM + 2 * DIM)[lane];
        float n2  = wave_sum(v.x * v.x + v.y * v.y);
        float pb0 = wave_sum(v.x * b0.x + v.y * b0.y);
        float pc0 = wave_sum(v.x * c0.x + v.y * c0.y);
        float pb1 = wave_sum(v.x * b1.x + v.y * b1.y);
        float pc1 = wave_sum(v.x * c1.x + v.y * c1.y);
        if (lane == 0) {
            relnorm2[wid] = n2;
            rdB[wid] = pb0;        rdC[wid] = pc0;
            rdB[NREL + wid] = pb1; rdC[NREL + wid] = pc1;
        }
    } else {
        int n = (b - RELU_BLOCKS - PRE_BLOCKS) * 256 + threadIdx.x;
        if (n <= NNODE) {
            int lo = 0, hi = NEDGE;
            while (lo < hi) {
                int mid = (lo + hi) >> 1;
                if (adj_src[mid] < n) lo = mid + 1; else hi = mid;
            }
            row_ptr[n] = lo;
        }
    }
}

// per-edge scalar precompute for both layers:
// ed[e] = { sc*rdC[r], 2sc^2*rdB[r], 2sc^2, bits(dst<<11 | r) }
__global__ void k_edges(const float* __restrict__ sp_val, const int* __restrict__ sp_rel,
                        const int* __restrict__ adj_dst,
                        const float* __restrict__ relnorm2,
                        const float* __restrict__ rdB, const float* __restrict__ rdC,
                        float4* __restrict__ ed0, float4* __restrict__ ed1) {
    int e = blockIdx.x * blockDim.x + threadIdx.x;
    if (e >= NEDGE) return;
    float v = sp_val[e];
    int r = sp_rel[e];
    float n2 = relnorm2[r];
    float sc = v * rsqrtf(fmaxf(v * v * n2, 1e-12f));
    float q2 = 2.f * sc * sc;
    unsigned pk = ((unsigned)adj_dst[e] << 11) | (unsigned)r;
    float pkf = __uint_as_float(pk);
    ed0[e] = make_float4(sc * rdC[r],        q2 * rdB[r],        q2, pkf);
    ed1[e] = make_float4(sc * rdC[NREL + r], q2 * rdB[NREL + r], q2, pkf);
}

// 4 nodes per wave, one 16-lane group per node; serial edge loop with 1-deep
// prefetch and online softmax; no cross-group merge. Epilogue writes f32 slice
// (+ bf16 mirror and next-layer self/neigh dots when WRITE_NEXT).
template<int USE_ED, int WRITE_NEXT>
__global__ void k_gat(const unsigned short* __restrict__ fin_m,
                      float* __restrict__ fout,
                      unsigned short* __restrict__ fout_m,
                      const unsigned short* __restrict__ relm,
                      const float4* __restrict__ edata,
                      const int* __restrict__ adj_dst, const int* __restrict__ sp_rel,
                      const float* __restrict__ sp_val, const float* __restrict__ relnorm2,
                      const float* __restrict__ rdB, const float* __restrict__ rdC,
                      const float* __restrict__ selfdot, const float* __restrict__ neighdot,
                      const int* __restrict__ row_ptr,
                      float* __restrict__ sd_n, float* __restrict__ nd_n,
                      const float* __restrict__ ak_next) {
    int wv = (blockIdx.x * blockDim.x + threadIdx.x) >> 6;
    int lane = threadIdx.x & 63;
    int g = lane >> 4, gl = lane & 15;
    int node = wv * 4 + g;
    if (node >= NNODE) return;
    int e0 = row_ptr[node], e1 = row_ptr[node + 1];
    float sd = selfdot[node];

    f32x2 acc0 = 0.f, acc1 = 0.f, acc2 = 0.f, acc3 = 0.f;
    float m = -3.0e38f, s = 0.f;

    uint4 fb = make_uint4(0, 0, 0, 0), rb = make_uint4(0, 0, 0, 0);
    float ab = 0.f, qb = 0.f, q2 = 0.f;
    int e = e0;
    if (e < e1) {
        int dst, r;
        if (USE_ED) {
            float4 ed = edata[e];
            unsigned pk = __float_as_uint(ed.w);
            dst = (int)(pk >> 11); r = (int)(pk & 2047u);
            ab = sd + ed.x + neighdot[dst];
            qb = ed.y; q2 = ed.z;
        } else {
            dst = adj_dst[e]; r = sp_rel[e];
            float v = sp_val[e];
            float sc = v * rsqrtf(fmaxf(v * v * relnorm2[r], 1e-12f));
            q2 = 2.f * sc * sc;
            qb = q2 * rdB[r];
            ab = sd + sc * rdC[r] + neighdot[dst];
        }
        fb = *reinterpret_cast<const uint4*>(fin_m + (size_t)dst * DIM + gl * 8);
        rb = *reinterpret_cast<const uint4*>(relm + (size_t)r * DIM + gl * 8);
    }
    while (e < e1) {
        int en = e + 1;
        bool more = en < e1;
        uint4 fb2 = make_uint4(0, 0, 0, 0), rb2 = make_uint4(0, 0, 0, 0);
        float ab2 = 0.f, qb2 = 0.f, q22 = 0.f;
        if (more) {   // prefetch next edge before this edge's dependent chain
            int dst, r;
            if (USE_ED) {
                float4 ed = edata[en];
                unsigned pk = __float_as_uint(ed.w);
                dst = (int)(pk >> 11); r = (int)(pk & 2047u);
                ab2 = sd + ed.x + neighdot[dst];
                qb2 = ed.y; q22 = ed.z;
            } else {
                dst = adj_dst[en]; r = sp_rel[en];
                float v = sp_val[en];
                float sc = v * rsqrtf(fmaxf(v * v * relnorm2[r], 1e-12f));
                q22 = 2.f * sc * sc;
                qb2 = q22 * rdB[r];
                ab2 = sd + sc * rdC[r] + neighdot[dst];
            }
            fb2 = *reinterpret_cast<const uint4*>(fin_m + (size_t)dst * DIM + gl * 8);
            rb2 = *reinterpret_cast<const uint4*>(relm + (size_t)r * DIM + gl * 8);
        }
        f32x2 f0 = bf2(fb.x), f1 = bf2(fb.y), f2 = bf2(fb.z), f3 = bf2(fb.w);
        f32x2 r0 = bf2(rb.x), r1 = bf2(rb.y), r2 = bf2(rb.z), r3 = bf2(rb.w);
        f32x2 d2 = f0 * r0;
        d2 += f1 * r1;
        d2 += f2 * r2;
        d2 += f3 * r3;
        float dot = d2.x + d2.y;
        dot += __shfl_xor(dot, 1, 64);
        dot += __shfl_xor(dot, 2, 64);
        dot += __shfl_xor(dot, 4, 64);
        dot += __shfl_xor(dot, 8, 64);
        float att = ab - dot * qb;
        float k2 = dot * q2;
        float nm = fmaxf(m, att);
        float corr = __expf(m - nm);
        float w = __expf(att - nm);
        s = s * corr + w;
        acc0 = acc0 * corr + w * (f0 - k2 * r0);
        acc1 = acc1 * corr + w * (f1 - k2 * r1);
        acc2 = acc2 * corr + w * (f2 - k2 * r2);
        acc3 = acc3 * corr + w * (f3 - k2 * r3);
        m = nm;
        e = en;
        fb = fb2; rb = rb2; ab = ab2; qb = qb2; q2 = q22;
    }

    float inv = (s > 0.f) ? 1.f / s : 0.f;
    float o[8];
    o[0] = fmaxf(acc0.x * inv, 0.f); o[1] = fmaxf(acc0.y * inv, 0.f);
    o[2] = fmaxf(acc1.x * inv, 0.f); o[3] = fmaxf(acc1.y * inv, 0.f);
    o[4] = fmaxf(acc2.x * inv, 0.f); o[5] = fmaxf(acc2.y * inv, 0.f);
    o[6] = fmaxf(acc3.x * inv, 0.f); o[7] = fmaxf(acc3.y * inv, 0.f);
    float4* op = reinterpret_cast<float4*>(fout + (size_t)node * OUTC + gl * 8);
    op[0] = make_float4(o[0], o[1], o[2], o[3]);
    op[1] = make_float4(o[4], o[5], o[6], o[7]);
    if (WRITE_NEXT) {
        uint4 mw;
        mw.x = pack2(o[0], o[1]); mw.y = pack2(o[2], o[3]);
        mw.z = pack2(o[4], o[5]); mw.w = pack2(o[6], o[7]);
        *reinterpret_cast<uint4*>(fout_m + (size_t)node * DIM + gl * 8) = mw;
        // next-layer per-node dots from the fresh output (16-lane reduce)
        const float4* aA = reinterpret_cast<const float4*>(ak_next) + gl * 2;
        const float4* aB = reinterpret_cast<const float4*>(ak_next + DIM) + gl * 2;
        float4 a0 = aA[0], a1 = aA[1], b0 = aB[0], b1 = aB[1];
        float pa = o[0] * a0.x + o[1] * a0.y + o[2] * a0.z + o[3] * a0.w
                 + o[4] * a1.x + o[5] * a1.y + o[6] * a1.z + o[7] * a1.w;
        float pb = o[0] * b0.x + o[1] * b0.y + o[2] * b0.z + o[3] * b0.w
                 + o[4] * b1.x + o[5] * b1.y + o[6] * b1.z + o[7] * b1.w;
#pragma unroll
        for (int off = 1; off <= 8; off <<= 1) {
            pa += __shfl_xor(pa, off, 64);
            pb += __shfl_xor(pb, off, 64);
        }
        if (gl == 0) { sd_n[node] = pa; nd_n[node] = pb; }
    }
}

extern "C" void kernel_launch(void* const* d_in, const int* in_sizes, int n_in,
                              void* d_out, int out_size, void* d_ws, size_t ws_size,
                              hipStream_t stream) {
    const float* features = (const float*)d_in[0];
    const float* rel_emb  = (const float*)d_in[1];
    const float* sp_val   = (const float*)d_in[2];
    const float* attn     = (const float*)d_in[3];
    const int*   adj_src  = (const int*)d_in[4];
    const int*   adj_dst  = (const int*)d_in[5];
    const int*   sp_rel   = (const int*)d_in[6];
    // d_in[7] = sp_row = arange(E) -> identity segment_sum, unused
    float* out = (float*)d_out;

    char* p = (char*)d_ws;
    unsigned short* mir0 = (unsigned short*)p; p += (size_t)NNODE * DIM * 2;
    unsigned short* mir1 = (unsigned short*)p; p += (size_t)NNODE * DIM * 2;
    unsigned short* relm = (unsigned short*)p; p += (size_t)NREL * DIM * 2;
    float* sd0      = (float*)p; p += (size_t)NNODE * 4;
    float* nd0      = (float*)p; p += (size_t)NNODE * 4;
    float* sd1      = (float*)p; p += (size_t)NNODE * 4;
    float* nd1      = (float*)p; p += (size_t)NNODE * 4;
    float* relnorm2 = (float*)p; p += (size_t)NREL * 4;
    float* rdB      = (float*)p; p += (size_t)2 * NREL * 4;
    float* rdC      = (float*)p; p += (size_t)2 * NREL * 4;
    int*   row_ptr  = (int*)p;   p += (size_t)(NNODE + 1) * 4;
    p = (char*)(((uintptr_t)p + 15) & ~(uintptr_t)15);
    float4* ed0 = (float4*)p; p += (size_t)NEDGE * 16;
    float4* ed1 = (float4*)p; p += (size_t)NEDGE * 16;
    size_t needed = (size_t)(p - (char*)d_ws);
    bool use_ed = (ws_size >= needed);   // constant across calls -> deterministic

    k_setup<<<RELU_BLOCKS + PRE_BLOCKS + ROW_BLOCKS, 256, 0, stream>>>(
        features, rel_emb, attn, adj_src, out, mir0, relm,
        relnorm2, rdB, rdC, sd0, nd0, row_ptr);

    int gat_blocks = (NNODE / 4 * 64) / 256;  // 6250

    if (use_ed) {
        k_edges<<<(NEDGE + 255) / 256, 256, 0, stream>>>(
            sp_val, sp_rel, adj_dst, relnorm2, rdB, rdC, ed0, ed1);
        k_gat<1, 1><<<gat_blocks, 256, 0, stream>>>(
            mir0, out + DIM, mir1, relm, ed0, adj_dst, sp_rel, sp_val, relnorm2,
            rdB, rdC, sd0, nd0, row_ptr, sd1, nd1, attn + 3 * DIM);
        k_gat<1, 0><<<gat_blocks, 256, 0, stream>>>(
            mir1, out + 2 * DIM, (unsigned short*)nullptr, relm, ed1, adj_dst, sp_rel,
            sp_val, relnorm2, rdB + NREL, rdC + NREL, sd1, nd1, row_ptr,
            (float*)nullptr, (float*)nullptr, (const float*)nullptr);
    } else {
        k_gat<0, 1><<<gat_blocks, 256, 0, stream>>>(
            mir0, out + DIM, mir1, relm, (const float4*)nullptr, adj_dst, sp_rel,
            sp_val, relnorm2, rdB, rdC, sd0, nd0, row_ptr, sd1, nd1, attn + 3 * DIM);
        k_gat<0, 0><<<gat_blocks, 256, 0, stream>>>(
            mir1, out + 2 * DIM, (unsigned short*)nullptr, relm, (const float4*)nullptr,
            adj_dst, sp_rel, sp_val, relnorm2, rdB + NREL, rdC + NREL, sd1, nd1, row_ptr,
            (float*)nullptr, (float*)nullptr, (const float*)nullptr);
    }
}